// Round 9
// baseline (514.291 us; speedup 1.0000x reference)
//
#include <hip/hip_runtime.h>
#include <stdint.h>
#include <cmath>

// RNN: h_{t+1} = tanh(x_t * w_in + h_t @ W_hh^T + (b_ih+b_hh)); out = h_T @ fc_W^T + fc_b
// B = out_size (8192), T = in_sizes[0]/B (4096), H = 10.
//
// R9 design (R7 structure, transcendental-free step):
//  * tanh(a) ~= u*Q(u^2), u = clamp(a/A, -1, 1), A = 3.8. All weights are
//    pre-scaled by 1/A so the MFMA output IS u (pre-clamp); the clamp is one
//    v_med3_f32 with inline +-1.0. Q = degree-7 poly in t=u^2, Estrin form:
//    chain = med3 -> sq -> fma -> fma -> fma -> mul (6 full-rate links,
//    ~30 cy) replacing exp2 -> add -> rcp (2 serial trans links, ~70-90 cy).
//    R8 lesson: serial LINK LATENCY is the cost driver, not pipe-issue.
//  * Coefficients are fit ON THE HOST each kernel_launch (Chebyshev
//    projection of tanh(A*u), 256 nodes, double precision, deterministic)
//    and passed as kernel args -- no memorized minimax constants.
//  * One wave = 16 batch elements; mfma_f32_16x16x16f16 D-fragment layout ==
//    B-fragment layout -> recurrence feeds itself, zero cross-lane ops.
//  * x: 8-step blocks, depth-2 software pipeline (R7).

#define H 10

typedef __fp16 h2 __attribute__((ext_vector_type(2)));
typedef __fp16 h4 __attribute__((ext_vector_type(4)));
typedef float  f4 __attribute__((ext_vector_type(4)));

#if __has_builtin(__builtin_amdgcn_cvt_pkrtz)
__device__ __forceinline__ h2 pk2(float a, float b) { return __builtin_amdgcn_cvt_pkrtz(a, b); }
#else
__device__ __forceinline__ h2 pk2(float a, float b) { h2 r; r.x = (__fp16)a; r.y = (__fp16)b; return r; }
#endif

#if __has_builtin(__builtin_amdgcn_fmed3f)
__device__ __forceinline__ float clamp11(float v) { return __builtin_amdgcn_fmed3f(v, -1.0f, 1.0f); }
#else
__device__ __forceinline__ float clamp11(float v) { return fminf(fmaxf(v, -1.0f), 1.0f); }
#endif

struct hpair { h2 lo, hi; };
__device__ __forceinline__ h4 mk_h4(h2 lo, h2 hi) {
    hpair p; p.lo = lo; p.hi = hi;
    return __builtin_bit_cast(h4, p);
}

// MFMA wrapper: body guarded by device-compile so BOTH passes see the same
// kernel symbol (R5 lesson: __has_builtin diverges host vs device).
__device__ __forceinline__ f4 mfma_16x16x16f16(h4 a, h4 b, f4 c) {
#if defined(__HIP_DEVICE_COMPILE__)
    return __builtin_amdgcn_mfma_f32_16x16x16f16(a, b, c, 0, 0, 0);
#else
    return c;
#endif
}

// One step: d = M*hb + c (all pre-scaled by 1/A); u = clamp(d); h = u*Q(u^2).
#define RNN_STEP(CF4)                                                         \
    do {                                                                      \
        f4 d = mfma_16x16x16f16(m_frag, hb, (CF4));                           \
        _Pragma("unroll")                                                     \
        for (int j = 0; j < 4; ++j) {                                         \
            float u  = clamp11(d[j]);                                         \
            float t  = u * u;                                                 \
            float e0 = __builtin_fmaf(t, q1, q0);                             \
            float e1 = __builtin_fmaf(t, q3, q2);                             \
            float e2 = __builtin_fmaf(t, q5, q4);                             \
            float e3 = __builtin_fmaf(t, q7, q6);                             \
            float t2 = t * t;                                                 \
            float f0 = __builtin_fmaf(t2, e1, e0);                            \
            float f1 = __builtin_fmaf(t2, e3, e2);                            \
            float t4 = t2 * t2;                                               \
            float Q  = __builtin_fmaf(t4, f1, f0);                            \
            hf[j] = u * Q;                                                    \
        }                                                                     \
        hb = mk_h4(pk2(hf[0], hf[1]), pk2(hf[2], hf[3]));                     \
    } while (0)

// Precompute 8 C-operands from two float4 x registers (independent of chain).
#define MAKE_C8(V0, V1)                                                       \
    do {                                                                      \
        float xs_[8] = {(V0).x, (V0).y, (V0).z, (V0).w,                       \
                        (V1).x, (V1).y, (V1).z, (V1).w};                      \
        _Pragma("unroll")                                                     \
        for (int s_ = 0; s_ < 8; ++s_) {                                      \
            c8[s_][0] = __builtin_fmaf(xs_[s_], winp[0], biasc[0]);           \
            c8[s_][1] = __builtin_fmaf(xs_[s_], winp[1], biasc[1]);           \
            c8[s_][2] = __builtin_fmaf(xs_[s_], winp[2], biasc[2]);           \
            c8[s_][3] = __builtin_fmaf(xs_[s_], winp[3], biasc[3]);           \
        }                                                                     \
    } while (0)

#define STEP8()                                                               \
    do {                                                                      \
        RNN_STEP(c8[0]); RNN_STEP(c8[1]); RNN_STEP(c8[2]); RNN_STEP(c8[3]);   \
        RNN_STEP(c8[4]); RNN_STEP(c8[5]); RNN_STEP(c8[6]); RNN_STEP(c8[7]);   \
    } while (0)

__global__ __launch_bounds__(64) void rnn_mfma_poly(
    const float* __restrict__ x,
    const float* __restrict__ W_ih,
    const float* __restrict__ W_hh,
    const float* __restrict__ b_ih,
    const float* __restrict__ b_hh,
    const float* __restrict__ fc_W,
    const float* __restrict__ fc_b,
    float* __restrict__ out,
    int B, int T, float invA,
    float q0, float q1, float q2, float q3,
    float q4, float q5, float q6, float q7)
{
    const int l = threadIdx.x;    // 0..63 (one wave per block)
    const int n = l & 15;         // batch-within-group; also A-row (unit m)
    const int g = l >> 4;         // k / unit sub-block
    const int b = blockIdx.x * 16 + n;

    // A fragment: M[m][k] = invA * W_hh[m][k], fp16. m = n, k = 4g+i.
    h4 m_frag;
#pragma unroll
    for (int i = 0; i < 4; ++i) {
        const int k = 4 * g + i;
        const float w = (n < H && k < H) ? invA * W_hh[n * H + k] : 0.0f;
        m_frag[i] = (__fp16)w;
    }

    // Per-lane constants for unit u = 4g+j (dead units -> 0).
    float winp[4], biasc[4], fcw[4];
#pragma unroll
    for (int j = 0; j < 4; ++j) {
        const int u = 4 * g + j;
        const bool live = (u < H);
        winp[j]  = live ? invA * W_ih[u] : 0.0f;
        biasc[j] = live ? invA * (b_ih[u] + b_hh[u]) : 0.0f;
        fcw[j]   = live ? fc_W[u] : 0.0f;
    }

    const __fp16 z16 = (__fp16)0.0f;
    h4 hb = {z16, z16, z16, z16};               // B fragment (fp16 h)
    float hf[4] = {0.f, 0.f, 0.f, 0.f};        // fp32 h (epilogue)
    f4 c8[8];

    const int brow = (b < B) ? b : (B - 1);
    const float* xr = x + (size_t)brow * (size_t)T;

    // ---- main loop: 8-step blocks, depth-2 pipelined x loads ----
    int t = 0;
    if (((T & 7) == 0) && T >= 24) {
        const int nb = T >> 3;   // number of 8-step blocks (>= 3 here)
        float4 a0 = *(const float4*)(xr + 0);
        float4 a1 = *(const float4*)(xr + 4);
        float4 b0 = *(const float4*)(xr + 8);
        float4 b1 = *(const float4*)(xr + 12);
        for (int blk = 0; blk < nb - 2; ++blk) {
            const float* xf = xr + 8 * (blk + 2);
            float4 f0 = *(const float4*)(xf);
            float4 f1 = *(const float4*)(xf + 4);
            MAKE_C8(a0, a1);
            STEP8();
            a0 = b0; a1 = b1;
            b0 = f0; b1 = f1;
        }
        MAKE_C8(a0, a1);
        STEP8();
        MAKE_C8(b0, b1);
        STEP8();
        t = T;
    }
    for (; t < T; ++t) {          // generic fallback / remainder
        float xq = xr[t];
        f4 cg;
        cg[0] = __builtin_fmaf(xq, winp[0], biasc[0]);
        cg[1] = __builtin_fmaf(xq, winp[1], biasc[1]);
        cg[2] = __builtin_fmaf(xq, winp[2], biasc[2]);
        cg[3] = __builtin_fmaf(xq, winp[3], biasc[3]);
        RNN_STEP(cg);
    }

    // Epilogue: FC partial over this lane's 4 units (fp32 h), reduce over g.
    float acc = 0.0f;
#pragma unroll
    for (int j = 0; j < 4; ++j) acc = __builtin_fmaf(hf[j], fcw[j], acc);
    acc += __shfl_xor(acc, 16, 64);
    acc += __shfl_xor(acc, 32, 64);
    if (g == 0 && b < B) out[b] = acc + fc_b[0];
}

// Host-side: Chebyshev fit of tanh(A*u) on u in [-1,1] as u*Q(u^2),
// Q = degree-7 monomial poly in t=u^2. Double precision, deterministic.
static void fit_tanh_poly(double A, float q[8]) {
    const int M = 256;
    const int NMAX = 15;                 // odd degrees 1..15 in u
    double c[NMAX + 1] = {0};
    for (int k = 1; k <= NMAX; k += 2) {
        double s = 0.0;
        for (int m = 0; m < M; ++m) {
            double th = M_PI * (m + 0.5) / M;
            s += tanh(A * cos(th)) * cos(k * th);
        }
        c[k] = 2.0 * s / M;
    }
    // Convert sum_k c_k T_k(u) (odd k) to monomial coefficients of u^j.
    double mono[NMAX + 1] = {0};
    double Tprev[NMAX + 1] = {0}, Tcur[NMAX + 1] = {0}, Tnext[NMAX + 1];
    Tprev[0] = 1.0;                       // T0
    Tcur[1]  = 1.0;                       // T1
    for (int k = 1; k <= NMAX; ++k) {
        if (k & 1)
            for (int j = 0; j <= k; ++j) mono[j] += c[k] * Tcur[j];
        for (int j = 0; j <= NMAX; ++j) Tnext[j] = -Tprev[j];
        for (int j = NMAX; j >= 1; --j) Tnext[j] += 2.0 * Tcur[j - 1];
        for (int j = 0; j <= NMAX; ++j) { Tprev[j] = Tcur[j]; Tcur[j] = Tnext[j]; }
    }
    for (int i = 0; i < 8; ++i) q[i] = (float)mono[2 * i + 1];  // u^(2i+1) -> t^i
}

extern "C" void kernel_launch(void* const* d_in, const int* in_sizes, int n_in,
                              void* d_out, int out_size, void* d_ws, size_t ws_size,
                              hipStream_t stream) {
    const float* x    = (const float*)d_in[0];
    const float* W_ih = (const float*)d_in[1];
    const float* W_hh = (const float*)d_in[2];
    const float* b_ih = (const float*)d_in[3];
    const float* b_hh = (const float*)d_in[4];
    const float* fc_W = (const float*)d_in[5];
    const float* fc_b = (const float*)d_in[6];
    float* out = (float*)d_out;

    const int B = out_size;              // 8192
    const int T = in_sizes[0] / B;       // 4096

    const double A = 3.8;                // clamp range; tanh(3.8)=0.99899
    float q[8];
    fit_tanh_poly(A, q);

    const int blocks = (B + 15) / 16;    // one wave = 16 batch elements
    rnn_mfma_poly<<<blocks, 64, 0, stream>>>(
        x, W_ih, W_hh, b_ih, b_hh, fc_W, fc_b, out, B, T, (float)(1.0 / A),
        q[0], q[1], q[2], q[3], q[4], q[5], q[6], q[7]);
}

// Round 10
// 469.424 us; speedup vs baseline: 1.0956x; 1.0956x over previous
//
#include <hip/hip_runtime.h>
#include <stdint.h>

// RNN: h_{t+1} = tanh(x_t * w_in + h_t @ W_hh^T + (b_ih+b_hh)); out = h_T @ fc_W^T + fc_b
// B = out_size (8192), T = in_sizes[0]/B (4096), H = 10.
//
// R10 design (R7 structure; trans-queue -> 1):
//  * Cost model calibrated by R8/R9: wall/step = MFMA-dep + nonlin tail,
//    nonlin tail = trans-pipe QUEUE (8 quarter-rate ops) + link latencies.
//    R9 (poly) cut the queue but doubled issue; R8 traded queue for links 1:1.
//  * tanh(a) = a(945+105t+t^2)/(945+420t+15t^2), t=a^2 — integer [5/4] Pade,
//    err <= 1.7e-3 on |a|<=4; a clamped by ONE v_med3_f32 (+-4.0 inline).
//  * ONE v_rcp_f32 per step for all 4 units: q = rcp(D0*D1*D2*D3),
//    h_j = (a_j*N_j * D_pair * s_other) * q — partial products off-tail.
//    Tail: med3->t->fma->fma->s01->full->rcp->mul->pack ~= 8 links + rcp.
//  * Self-feeding MFMA (D-fragment == B-fragment layout), 8-step x pipeline.

#define H 10

typedef __fp16 h2 __attribute__((ext_vector_type(2)));
typedef __fp16 h4 __attribute__((ext_vector_type(4)));
typedef float  f4 __attribute__((ext_vector_type(4)));

#if __has_builtin(__builtin_amdgcn_rcpf)
__device__ __forceinline__ float fast_rcp(float x) { return __builtin_amdgcn_rcpf(x); }
#else
__device__ __forceinline__ float fast_rcp(float x) { return 1.0f / x; }
#endif

#if __has_builtin(__builtin_amdgcn_cvt_pkrtz)
__device__ __forceinline__ h2 pk2(float a, float b) { return __builtin_amdgcn_cvt_pkrtz(a, b); }
#else
__device__ __forceinline__ h2 pk2(float a, float b) { h2 r; r.x = (__fp16)a; r.y = (__fp16)b; return r; }
#endif

#if __has_builtin(__builtin_amdgcn_fmed3f)
__device__ __forceinline__ float clamp4(float v) { return __builtin_amdgcn_fmed3f(v, -4.0f, 4.0f); }
#else
__device__ __forceinline__ float clamp4(float v) { return fminf(fmaxf(v, -4.0f), 4.0f); }
#endif

struct hpair { h2 lo, hi; };
__device__ __forceinline__ h4 mk_h4(h2 lo, h2 hi) {
    hpair p; p.lo = lo; p.hi = hi;
    return __builtin_bit_cast(h4, p);
}

// MFMA wrapper: body guarded by device-compile so BOTH passes see the same
// kernel symbol (R5 lesson: __has_builtin diverges host vs device).
__device__ __forceinline__ f4 mfma_16x16x16f16(h4 a, h4 b, f4 c) {
#if defined(__HIP_DEVICE_COMPILE__)
    return __builtin_amdgcn_mfma_f32_16x16x16f16(a, b, c, 0, 0, 0);
#else
    return c;
#endif
}

// One step: d = W*h + c; h' = tanh~(d) via Pade[5/4] with ONE rcp.
#define RNN_STEP(CF4)                                                         \
    do {                                                                      \
        f4 d = mfma_16x16x16f16(m_frag, hb, (CF4));                           \
        float dc0 = clamp4(d[0]), dc1 = clamp4(d[1]);                         \
        float dc2 = clamp4(d[2]), dc3 = clamp4(d[3]);                         \
        float t0 = dc0 * dc0, t1 = dc1 * dc1;                                 \
        float t2 = dc2 * dc2, t3 = dc3 * dc3;                                 \
        /* numerators: an_j = dc_j * (945 + 105 t + t^2) */                   \
        float n0 = __builtin_fmaf(t0, t0 + 105.0f, 945.0f);                   \
        float n1 = __builtin_fmaf(t1, t1 + 105.0f, 945.0f);                   \
        float n2 = __builtin_fmaf(t2, t2 + 105.0f, 945.0f);                   \
        float n3 = __builtin_fmaf(t3, t3 + 105.0f, 945.0f);                   \
        float an0 = dc0 * n0, an1 = dc1 * n1;                                 \
        float an2 = dc2 * n2, an3 = dc3 * n3;                                 \
        /* denominators: D_j = 945 + 420 t + 15 t^2 */                        \
        float D0 = __builtin_fmaf(t0, __builtin_fmaf(t0, 15.0f, 420.0f), 945.0f); \
        float D1 = __builtin_fmaf(t1, __builtin_fmaf(t1, 15.0f, 420.0f), 945.0f); \
        float D2 = __builtin_fmaf(t2, __builtin_fmaf(t2, 15.0f, 420.0f), 945.0f); \
        float D3 = __builtin_fmaf(t3, __builtin_fmaf(t3, 15.0f, 420.0f), 945.0f); \
        /* one rcp for all four: q = 1/(D0 D1 D2 D3) */                       \
        float s01 = D0 * D1, s23 = D2 * D3;                                   \
        float q = fast_rcp(s01 * s23);                                        \
        /* h_j = an_j * D_partner * s_other * q (products off the tail) */    \
        float w0 = an0 * D1, w1 = an1 * D0;                                   \
        float w2 = an2 * D3, w3 = an3 * D2;                                   \
        float v0 = w0 * s23, v1 = w1 * s23;                                   \
        float v2 = w2 * s01, v3 = w3 * s01;                                   \
        hf[0] = v0 * q; hf[1] = v1 * q;                                       \
        hf[2] = v2 * q; hf[3] = v3 * q;                                       \
        hb = mk_h4(pk2(hf[0], hf[1]), pk2(hf[2], hf[3]));                     \
    } while (0)

// Precompute 8 C-operands from two float4 x registers (independent of chain).
#define MAKE_C8(V0, V1)                                                       \
    do {                                                                      \
        float xs_[8] = {(V0).x, (V0).y, (V0).z, (V0).w,                       \
                        (V1).x, (V1).y, (V1).z, (V1).w};                      \
        _Pragma("unroll")                                                     \
        for (int s_ = 0; s_ < 8; ++s_) {                                      \
            c8[s_][0] = __builtin_fmaf(xs_[s_], winp[0], biasc[0]);           \
            c8[s_][1] = __builtin_fmaf(xs_[s_], winp[1], biasc[1]);           \
            c8[s_][2] = __builtin_fmaf(xs_[s_], winp[2], biasc[2]);           \
            c8[s_][3] = __builtin_fmaf(xs_[s_], winp[3], biasc[3]);           \
        }                                                                     \
    } while (0)

#define STEP8()                                                               \
    do {                                                                      \
        RNN_STEP(c8[0]); RNN_STEP(c8[1]); RNN_STEP(c8[2]); RNN_STEP(c8[3]);   \
        RNN_STEP(c8[4]); RNN_STEP(c8[5]); RNN_STEP(c8[6]); RNN_STEP(c8[7]);   \
    } while (0)

__global__ __launch_bounds__(64) void rnn_mfma_pade(
    const float* __restrict__ x,
    const float* __restrict__ W_ih,
    const float* __restrict__ W_hh,
    const float* __restrict__ b_ih,
    const float* __restrict__ b_hh,
    const float* __restrict__ fc_W,
    const float* __restrict__ fc_b,
    float* __restrict__ out,
    int B, int T)
{
    const int l = threadIdx.x;    // 0..63 (one wave per block)
    const int n = l & 15;         // batch-within-group; also A-row
    const int g = l >> 4;         // unit sub-block
    const int b = blockIdx.x * 16 + n;

    // A fragment: A[m][k] = W_hh[m][k] (unscaled), fp16. m = n, k = 4g+i.
    h4 m_frag;
#pragma unroll
    for (int i = 0; i < 4; ++i) {
        const int k = 4 * g + i;
        const float w = (n < H && k < H) ? W_hh[n * H + k] : 0.0f;
        m_frag[i] = (__fp16)w;
    }

    // Per-lane constants for unit u = 4g+j (dead units -> 0).
    float winp[4], biasc[4], fcw[4];
#pragma unroll
    for (int j = 0; j < 4; ++j) {
        const int u = 4 * g + j;
        const bool live = (u < H);
        winp[j]  = live ? W_ih[u] : 0.0f;
        biasc[j] = live ? (b_ih[u] + b_hh[u]) : 0.0f;
        fcw[j]   = live ? fc_W[u] : 0.0f;
    }

    const __fp16 z16 = (__fp16)0.0f;
    h4 hb = {z16, z16, z16, z16};               // B fragment (fp16 h)
    float hf[4] = {0.f, 0.f, 0.f, 0.f};        // fp32 h (epilogue)
    f4 c8[8];

    const int brow = (b < B) ? b : (B - 1);
    const float* xr = x + (size_t)brow * (size_t)T;

    // ---- main loop: 8-step blocks, depth-2 pipelined x loads ----
    int t = 0;
    if (((T & 7) == 0) && T >= 24) {
        const int nb = T >> 3;   // number of 8-step blocks (>= 3 here)
        float4 a0 = *(const float4*)(xr + 0);
        float4 a1 = *(const float4*)(xr + 4);
        float4 b0 = *(const float4*)(xr + 8);
        float4 b1 = *(const float4*)(xr + 12);
        for (int blk = 0; blk < nb - 2; ++blk) {
            const float* xf = xr + 8 * (blk + 2);
            float4 f0 = *(const float4*)(xf);
            float4 f1 = *(const float4*)(xf + 4);
            MAKE_C8(a0, a1);
            STEP8();
            a0 = b0; a1 = b1;
            b0 = f0; b1 = f1;
        }
        MAKE_C8(a0, a1);
        STEP8();
        MAKE_C8(b0, b1);
        STEP8();
        t = T;
    }
    for (; t < T; ++t) {          // generic fallback / remainder
        float xq = xr[t];
        f4 cg;
        cg[0] = __builtin_fmaf(xq, winp[0], biasc[0]);
        cg[1] = __builtin_fmaf(xq, winp[1], biasc[1]);
        cg[2] = __builtin_fmaf(xq, winp[2], biasc[2]);
        cg[3] = __builtin_fmaf(xq, winp[3], biasc[3]);
        RNN_STEP(cg);
    }

    // Epilogue: FC partial over this lane's 4 units (fp32 h), reduce over g.
    float acc = 0.0f;
#pragma unroll
    for (int j = 0; j < 4; ++j) acc = __builtin_fmaf(hf[j], fcw[j], acc);
    acc += __shfl_xor(acc, 16, 64);
    acc += __shfl_xor(acc, 32, 64);
    if (g == 0 && b < B) out[b] = acc + fc_b[0];
}

extern "C" void kernel_launch(void* const* d_in, const int* in_sizes, int n_in,
                              void* d_out, int out_size, void* d_ws, size_t ws_size,
                              hipStream_t stream) {
    const float* x    = (const float*)d_in[0];
    const float* W_ih = (const float*)d_in[1];
    const float* W_hh = (const float*)d_in[2];
    const float* b_ih = (const float*)d_in[3];
    const float* b_hh = (const float*)d_in[4];
    const float* fc_W = (const float*)d_in[5];
    const float* fc_b = (const float*)d_in[6];
    float* out = (float*)d_out;

    const int B = out_size;              // 8192
    const int T = in_sizes[0] / B;       // 4096

    const int blocks = (B + 15) / 16;    // one wave = 16 batch elements
    rnn_mfma_pade<<<blocks, 64, 0, stream>>>(x, W_ih, W_hh, b_ih, b_hh,
                                             fc_W, fc_b, out, B, T);
}

// Round 12
// 253.714 us; speedup vs baseline: 2.0270x; 1.8502x over previous
//
#include <hip/hip_runtime.h>
#include <stdint.h>

// RNN: h_{t+1} = tanh(x_t * w_in + h_t @ W_hh^T + (b_ih+b_hh)); out = h_T @ fc_W^T + fc_b
// B = out_size (8192), T = in_sizes[0]/B (4096), H = 10.
//
// R12 design. Calibrated cost model (R7-R10): wall/step = floor(~100, MFMA
// dep+hazards) + 8cy per TRANS op + small VALU; trans<->VALU trades neutral.
// So cut trans count: PERMUTE units across MFMA rows so all 10 live units
// sit in D-regs j=0..2 -> 3 exp + 3 rcp per step (was 4+4).
//   unit_of_row = {0,4,8,-1, 1,5,9,-1, 2,6,-1,-1, 3,7,-1(x),-1}
// (rows {3,7,11,15} = D-reg j=3 all dead; col 14 carries C*w_in so x enters
// through the MFMA; bias + rowsum(W_hh) (r-recursion) ride in the
// loop-invariant C-operand; g==3 lanes' B hi-word is all dead-column -> x
// injected there with one precomputed pk2 + one cndmask.)
//  * r-recursion: r = 1/(1+exp2(a')), h = 1-2r; A = -2C*W_hh[perm] fp16.
//  * Self-feeding MFMA: D-fragment layout == B-fragment layout (R5-R11).
//  * x: 8-step blocks, depth-2 software pipeline; pk2(x,1) hoisted off-chain.

#define H 10

typedef __fp16 h2 __attribute__((ext_vector_type(2)));
typedef __fp16 h4 __attribute__((ext_vector_type(4)));
typedef float  f4 __attribute__((ext_vector_type(4)));

#if __has_builtin(__builtin_amdgcn_exp2f)
__device__ __forceinline__ float fast_exp2(float x) { return __builtin_amdgcn_exp2f(x); }
#else
__device__ __forceinline__ float fast_exp2(float x) { return __exp2f(x); }
#endif

#if __has_builtin(__builtin_amdgcn_rcpf)
__device__ __forceinline__ float fast_rcp(float x) { return __builtin_amdgcn_rcpf(x); }
#else
__device__ __forceinline__ float fast_rcp(float x) { return 1.0f / x; }
#endif

#if __has_builtin(__builtin_amdgcn_cvt_pkrtz)
__device__ __forceinline__ h2 pk2(float a, float b) { return __builtin_amdgcn_cvt_pkrtz(a, b); }
#else
__device__ __forceinline__ h2 pk2(float a, float b) { h2 r; r.x = (__fp16)a; r.y = (__fp16)b; return r; }
#endif

struct hpair { h2 lo, hi; };
__device__ __forceinline__ h4 mk_h4(h2 lo, h2 hi) {
    hpair p; p.lo = lo; p.hi = hi;
    return __builtin_bit_cast(h4, p);
}

// MFMA wrapper: body guarded by device-compile so BOTH passes see the same
// kernel symbol (R5 lesson: __has_builtin diverges host vs device).
__device__ __forceinline__ f4 mfma_16x16x16f16(h4 a, h4 b, f4 c) {
#if defined(__HIP_DEVICE_COMPILE__)
    return __builtin_amdgcn_mfma_f32_16x16x16f16(a, b, c, 0, 0, 0);
#else
    return c;
#endif
}

// One step. XPK = precomputed pk2(x_{t+1}, 1). rb holds [r_t | x_t] going in.
// On-chain: MFMA, 3 exp2, 3 add, 3 rcp, 2 pk2, 1 cndmask.
#define RNN_STEP(XPK)                                                         \
    do {                                                                      \
        f4 d = mfma_16x16x16f16(m_frag, rb, biasc);                           \
        float e0 = fast_exp2(d[0]);                                           \
        float e1 = fast_exp2(d[1]);                                           \
        float e2 = fast_exp2(d[2]);                                           \
        rf0 = fast_rcp(e0 + 1.0f);                                            \
        rf1 = fast_rcp(e1 + 1.0f);                                            \
        rf2 = fast_rcp(e2 + 1.0f);                                            \
        h2 lo = pk2(rf0, rf1);                                                \
        h2 hi = pk2(rf2, rf2);                                                \
        unsigned hiw = is_g3 ? __builtin_bit_cast(unsigned, (XPK))            \
                             : __builtin_bit_cast(unsigned, hi);              \
        rb = mk_h4(lo, __builtin_bit_cast(h2, hiw));                          \
    } while (0)

__global__ __launch_bounds__(64) void rnn_mfma_perm(
    const float* __restrict__ x,
    const float* __restrict__ W_ih,
    const float* __restrict__ W_hh,
    const float* __restrict__ b_ih,
    const float* __restrict__ b_hh,
    const float* __restrict__ fc_W,
    const float* __restrict__ fc_b,
    float* __restrict__ out,
    int B, int T)
{
    const int l = threadIdx.x;    // 0..63 (one wave per block)
    const int n = l & 15;         // batch col; also A-row index
    const int g = l >> 4;         // k sub-block
    const int b = blockIdx.x * 16 + n;
    const bool is_g3 = (g == 3);

    const float C = 2.8853900817779268f;  // 2*log2(e)

    // Row/col permutation: unit_of_row[r] = original unit index or -1 (dead).
    // Live units fill D-regs j=0..2; reg j=3 rows {3,7,11,15} all dead.
    // Column 14 = x column (C*w_in).
    const int uor[16] = {0, 4, 8, -1,  1, 5, 9, -1,  2, 6, -1, -1,  3, 7, -1, -1};

    // A fragment: lane (g,n) holds A[n][4g+i].
    const int ur = uor[n];        // this A-row's unit (or -1)
    h4 m_frag;
#pragma unroll
    for (int i = 0; i < 4; ++i) {
        const int k = 4 * g + i;
        float w = 0.0f;
        if (ur >= 0) {
            if (k == 14)            w = C * W_ih[ur];
            else if (uor[k] >= 0)   w = -2.0f * C * W_hh[ur * H + uor[k]];
        }
        m_frag[i] = (__fp16)w;
    }

    // Loop-invariant C-operand: biasc[j] for row 4g+j:
    // C*(b_ih+b_hh+rowsum(W_hh)) of that row's unit (r-recursion absorbs W*1).
    f4 biasc;
    float fcw[4];
#pragma unroll
    for (int j = 0; j < 4; ++j) {
        const int u = uor[4 * g + j];
        float rowsum = 0.0f;
        if (u >= 0) {
#pragma unroll
            for (int k = 0; k < H; ++k) rowsum += W_hh[u * H + k];
        }
        biasc[j] = (u >= 0) ? C * (b_ih[u] + b_hh[u] + rowsum) : 0.0f;
        fcw[j]   = (u >= 0) ? fc_W[u] : 0.0f;
    }

    float rf0 = 0.5f, rf1 = 0.5f, rf2 = 0.5f;   // r = 0.5 <=> h = 0
    h2 halfpk = pk2(0.5f, 0.5f);
    h4 rb;                                       // primed with x_0 below

    const int brow = (b < B) ? b : (B - 1);
    const float* xr = x + (size_t)brow * (size_t)T;

    int t = 0;
    if (((T & 7) == 0) && T >= 24) {
        const int nb = T >> 3;
        float4 a0 = *(const float4*)(xr + 0);
        float4 a1 = *(const float4*)(xr + 4);
        rb = mk_h4(halfpk, is_g3 ? pk2(a0.x, 1.0f) : halfpk);   // [r0=.5 | x_0]
        float4 b0 = *(const float4*)(xr + 8);
        float4 b1 = *(const float4*)(xr + 12);
        for (int blk = 0; blk < nb - 2; ++blk) {
            const float* xf = xr + 8 * (blk + 2);
            float4 f0 = *(const float4*)(xf);
            float4 f1 = *(const float4*)(xf + 4);
            // precompute pk2 of x for steps t+1..t+8 (off the serial chain)
            h2 xp0 = pk2(a0.y, 1.0f), xp1 = pk2(a0.z, 1.0f);
            h2 xp2 = pk2(a0.w, 1.0f), xp3 = pk2(a1.x, 1.0f);
            h2 xp4 = pk2(a1.y, 1.0f), xp5 = pk2(a1.z, 1.0f);
            h2 xp6 = pk2(a1.w, 1.0f), xp7 = pk2(b0.x, 1.0f);
            RNN_STEP(xp0); RNN_STEP(xp1); RNN_STEP(xp2); RNN_STEP(xp3);
            RNN_STEP(xp4); RNN_STEP(xp5); RNN_STEP(xp6); RNN_STEP(xp7);
            a0 = b0; a1 = b1;
            b0 = f0; b1 = f1;
        }
        {   // last two blocks; final step installs dummy x
            h2 xp0 = pk2(a0.y, 1.0f), xp1 = pk2(a0.z, 1.0f);
            h2 xp2 = pk2(a0.w, 1.0f), xp3 = pk2(a1.x, 1.0f);
            h2 xp4 = pk2(a1.y, 1.0f), xp5 = pk2(a1.z, 1.0f);
            h2 xp6 = pk2(a1.w, 1.0f), xp7 = pk2(b0.x, 1.0f);
            RNN_STEP(xp0); RNN_STEP(xp1); RNN_STEP(xp2); RNN_STEP(xp3);
            RNN_STEP(xp4); RNN_STEP(xp5); RNN_STEP(xp6); RNN_STEP(xp7);
            h2 yp0 = pk2(b0.y, 1.0f), yp1 = pk2(b0.z, 1.0f);
            h2 yp2 = pk2(b0.w, 1.0f), yp3 = pk2(b1.x, 1.0f);
            h2 yp4 = pk2(b1.y, 1.0f), yp5 = pk2(b1.z, 1.0f);
            h2 yp6 = pk2(b1.w, 1.0f), yp7 = pk2(0.0f, 1.0f);
            RNN_STEP(yp0); RNN_STEP(yp1); RNN_STEP(yp2); RNN_STEP(yp3);
            RNN_STEP(yp4); RNN_STEP(yp5); RNN_STEP(yp6); RNN_STEP(yp7);
        }
        t = T;
    } else {
        rb = mk_h4(halfpk, is_g3 ? pk2((T > 0) ? xr[0] : 0.0f, 1.0f) : halfpk);
    }
    for (; t < T; ++t) {          // generic fallback (T not multiple of 8)
        float xnext = (t + 1 < T) ? xr[t + 1] : 0.0f;
        h2 xp = pk2(xnext, 1.0f);
        RNN_STEP(xp);
    }

    // Epilogue: h = 1 - 2r for this lane's 3 (possibly dead) units; FC+reduce.
    float acc = 0.0f;
    acc = __builtin_fmaf(__builtin_fmaf(-2.0f, rf0, 1.0f), fcw[0], acc);
    acc = __builtin_fmaf(__builtin_fmaf(-2.0f, rf1, 1.0f), fcw[1], acc);
    acc = __builtin_fmaf(__builtin_fmaf(-2.0f, rf2, 1.0f), fcw[2], acc);
    acc += __shfl_xor(acc, 16, 64);
    acc += __shfl_xor(acc, 32, 64);
    if (g == 0 && b < B) out[b] = acc + fc_b[0];
}

extern "C" void kernel_launch(void* const* d_in, const int* in_sizes, int n_in,
                              void* d_out, int out_size, void* d_ws, size_t ws_size,
                              hipStream_t stream) {
    const float* x    = (const float*)d_in[0];
    const float* W_ih = (const float*)d_in[1];
    const float* W_hh = (const float*)d_in[2];
    const float* b_ih = (const float*)d_in[3];
    const float* b_hh = (const float*)d_in[4];
    const float* fc_W = (const float*)d_in[5];
    const float* fc_b = (const float*)d_in[6];
    float* out = (float*)d_out;

    const int B = out_size;              // 8192
    const int T = in_sizes[0] / B;       // 4096

    const int blocks = (B + 15) / 16;    // one wave = 16 batch elements
    rnn_mfma_perm<<<blocks, 64, 0, stream>>>(x, W_ih, W_hh, b_ih, b_hh,
                                             fc_W, fc_b, out, B, T);
}